// Round 12
// baseline (3415.808 us; speedup 1.0000x reference)
//
#include <hip/hip_runtime.h>

#define TOK 4096
#define SEQ 512
#define BATCH 8
#define DIM 512
#define NHEAD 8
#define DK 64
#define FFD 2048
#define RPW 4
#define RPB 16
#define TP 68   // tile pitch: 68%32=4 -> b128 conflict-free, 16B aligned

typedef unsigned short u16;
typedef float floatx4 __attribute__((ext_vector_type(4)));
typedef short shortx8 __attribute__((ext_vector_type(8)));

__device__ __forceinline__ u16 bfh(float f) {
    union { float f; unsigned u; } x; x.f = f;
    return (u16)((x.u + 0x7fffu + ((x.u >> 16) & 1u)) >> 16);
}
__device__ __forceinline__ float bff(u16 h) {
    union { unsigned u; float f; } x; x.u = (unsigned)h << 16; return x.f;
}
__device__ __forceinline__ float wave_max(float v) {
    #pragma unroll
    for (int off = 32; off; off >>= 1) v = fmaxf(v, __shfl_xor(v, off, 64));
    return v;
}
__device__ __forceinline__ float wave_sum(float v) {
    #pragma unroll
    for (int off = 32; off; off >>= 1) v += __shfl_xor(v, off, 64);
    return v;
}

__global__ void VAKT_52226802319686_kernel(float* out, int n) {
    int i = blockIdx.x * 256 + threadIdx.x;
    if (i < n) out[i] = 524288.f;
}

__global__ void embed_r12(const int* cd, const int* cad, const float* cemb,
                          const float* caemb, float* x0, float* y) {
    int tok = blockIdx.x;
    int idx = cd[tok];
    int resp = (cad[tok] - idx) / 1000;
    for (int d = threadIdx.x; d < DIM; d += 256) {
        float e = cemb[(size_t)idx * DIM + d];
        x0[(size_t)tok * DIM + d] = e;
        y[(size_t)tok * DIM + d] = e + caemb[resp * DIM + d];
    }
}

__global__ void concat_r12(const float* X, const float* X0, float* H) {
    int tok = blockIdx.x;
    for (int d = threadIdx.x; d < 2 * DIM; d += 256) {
        H[(size_t)tok * (2 * DIM) + d] =
            (d < DIM) ? X[(size_t)tok * DIM + d] : X0[(size_t)tok * DIM + (d - DIM)];
    }
}

__global__ void add_ln_r12(const float* X, const float* Dl, const float* sc,
                           const float* bi, float* O) {
    int lane = threadIdx.x & 63, w = threadIdx.x >> 6;
    size_t row = (size_t)blockIdx.x * 4 + w;
    const float* xr = X + row * DIM;
    const float* dr = Dl + row * DIM;
    float v[8]; float sum = 0.f, sq = 0.f;
    for (int i = 0; i < 8; i++) {
        int d = i * 64 + lane;
        float t = xr[d] + dr[d];
        v[i] = t; sum += t; sq += t * t;
    }
    sum = wave_sum(sum); sq = wave_sum(sq);
    float mean = sum * (1.0f / 512.0f);
    float var = sq * (1.0f / 512.0f) - mean * mean;
    float rstd = rsqrtf(var + 1e-5f);
    float* orow = O + row * DIM;
    for (int i = 0; i < 8; i++) {
        int d = i * 64 + lane;
        orow[d] = (v[i] - mean) * rstd * sc[d] + bi[d];
    }
}

// W[K][N] fp32 -> Bt hi/lo u16 [N][K] (transposed + bf16-split)
__global__ __launch_bounds__(256) void wsplit(const float* W, u16* Bh, u16* Bl,
                                              int N, int K) {
    __shared__ float T[64][65];
    int t = threadIdx.x;
    int k0 = blockIdx.x * 64, n0 = blockIdx.y * 64;
    for (int i = 0; i < 16; i++) {
        int idx = i * 256 + t;
        int kr = idx >> 6, nc = idx & 63;
        int gn = n0 + nc;
        T[kr][nc] = (gn < N) ? W[(size_t)(k0 + kr) * N + gn] : 0.f;
    }
    __syncthreads();
    for (int i = 0; i < 16; i++) {
        int idx = i * 256 + t;
        int nr = idx >> 6, kc = idx & 63;
        float v = T[kc][nr];
        u16 h = bfh(v);
        float rem = v - bff(h);
        size_t o = (size_t)(n0 + nr) * K + k0 + kc;
        Bh[o] = h; Bl[o] = bfh(rem);
    }
}

// C[4096,N] = A @ Bt^T + bias. mode: 0=bias, 1=bias+relu, 2=accumulate.
// bias: col<nsplit -> biasA[col], else biasB[col-nsplit].
__global__ __launch_bounds__(256) void gemm_mf(const float* A, const u16* Bth, const u16* Btl,
                                               int Krow, int koff,
                                               const float* biasA, const float* biasB, int nsplit,
                                               float* C, int N, int K, int mode) {
    __shared__ u16 Ah[64][40], Al[64][40];
    const int t = threadIdx.x;
    const int lane = t & 63, w = t >> 6;
    const int l16 = lane & 15, quad = lane >> 4;
    const int bm0 = blockIdx.y * 64, bn0 = blockIdx.x * 64;
    const int wm = (w & 1) * 32, wn = (w >> 1) * 32;
    const int ar = t >> 2, ac = (t & 3) * 8;

    floatx4 acc[2][2];
    #pragma unroll
    for (int mi = 0; mi < 2; mi++)
        #pragma unroll
        for (int ni = 0; ni < 2; ni++) acc[mi][ni] = (floatx4){0.f, 0.f, 0.f, 0.f};

    for (int k0 = 0; k0 < K; k0 += 32) {
        __syncthreads();
        {
            const float* src = A + (size_t)(bm0 + ar) * K + k0 + ac;
            float4 v0 = ((const float4*)src)[0];
            float4 v1 = ((const float4*)src)[1];
            float vv[8] = {v0.x, v0.y, v0.z, v0.w, v1.x, v1.y, v1.z, v1.w};
            unsigned hp[4], lp[4];
            #pragma unroll
            for (int i = 0; i < 4; i++) {
                u16 h0 = bfh(vv[2*i]),   l0 = bfh(vv[2*i]   - bff(bfh(vv[2*i])));
                u16 h1 = bfh(vv[2*i+1]), l1 = bfh(vv[2*i+1] - bff(bfh(vv[2*i+1])));
                hp[i] = (unsigned)h0 | ((unsigned)h1 << 16);
                lp[i] = (unsigned)l0 | ((unsigned)l1 << 16);
            }
            *(uint4*)&Ah[ar][ac] = make_uint4(hp[0], hp[1], hp[2], hp[3]);
            *(uint4*)&Al[ar][ac] = make_uint4(lp[0], lp[1], lp[2], lp[3]);
        }
        __syncthreads();
        shortx8 ahf[2], alf[2], bhf[2], blf[2];
        #pragma unroll
        for (int mi = 0; mi < 2; mi++) {
            ahf[mi] = *(const shortx8*)&Ah[wm + mi * 16 + l16][quad * 8];
            alf[mi] = *(const shortx8*)&Al[wm + mi * 16 + l16][quad * 8];
        }
        #pragma unroll
        for (int ni = 0; ni < 2; ni++) {
            size_t o = (size_t)(bn0 + wn + ni * 16 + l16) * Krow + koff + k0 + quad * 8;
            bhf[ni] = *(const shortx8*)(Bth + o);
            blf[ni] = *(const shortx8*)(Btl + o);
        }
        #pragma unroll
        for (int mi = 0; mi < 2; mi++)
            #pragma unroll
            for (int ni = 0; ni < 2; ni++) {
                acc[mi][ni] = __builtin_amdgcn_mfma_f32_16x16x32_bf16(ahf[mi], bhf[ni], acc[mi][ni], 0, 0, 0);
                acc[mi][ni] = __builtin_amdgcn_mfma_f32_16x16x32_bf16(ahf[mi], blf[ni], acc[mi][ni], 0, 0, 0);
                acc[mi][ni] = __builtin_amdgcn_mfma_f32_16x16x32_bf16(alf[mi], bhf[ni], acc[mi][ni], 0, 0, 0);
            }
    }
    #pragma unroll
    for (int ni = 0; ni < 2; ni++) {
        int col = bn0 + wn + ni * 16 + l16;
        if (col < N) {
            float bv = 0.f;
            if (mode != 2) bv = (col < nsplit) ? biasA[col] : biasB[col - nsplit];
            #pragma unroll
            for (int mi = 0; mi < 2; mi++) {
                #pragma unroll
                for (int r = 0; r < 4; r++) {
                    int row = bm0 + wm + mi * 16 + quad * 4 + r;
                    size_t o = (size_t)row * N + col;
                    float v = acc[mi][ni][r] + bv;
                    if (mode == 1 && v < 0.f) v = 0.f;
                    if (mode == 2) v += C[o];
                    C[o] = v;
                }
            }
        }
    }
}

// LDS-tiled attention, all-b128 LDS traffic, strided Q/K/V.
__global__ __launch_bounds__(256) void attn_r12(const float* Q, int ldq,
                                                const float* Kf, int ldk,
                                                const float* V, int ldv,
                                                const float* gam, float* O, int mask0zp) {
    __shared__ float tile[64 * TP];
    __shared__ float qbuf[4][RPW][64];
    __shared__ float awbuf[4][64];
    const int t = threadIdx.x;
    const int lane = t & 63, w = t >> 6;
    const int g = lane >> 4, l4 = lane & 15;
    const int chunk = blockIdx.x, h = blockIdx.y, b = blockIdx.z;
    const size_t baseq = (size_t)b * SEQ * ldq + (size_t)h * DK;
    const size_t basek = (size_t)b * SEQ * ldk + (size_t)h * DK;
    const size_t basev = (size_t)b * SEQ * ldv + (size_t)h * DK;
    const size_t baseo = (size_t)b * SEQ * DIM + (size_t)h * DK;
    const int row0 = chunk * RPB + w * RPW;
    float gv = gam[h];
    float gamma = -((gv > 20.f) ? gv : log1pf(__expf(gv)));
    const int kmax_blk = chunk * RPB + RPB - 1 - (mask0zp ? 1 : 0);
    const int cmax_blk = kmax_blk >> 6;
    const int jr = t >> 2, d0 = (t & 3) * 16;

    #pragma unroll
    for (int r = 0; r < RPW; ++r)
        qbuf[w][r][lane] = Q[baseq + (size_t)(row0 + r) * ldq + lane];

    float s[RPW][8];
    #pragma unroll
    for (int r = 0; r < RPW; ++r)
        #pragma unroll
        for (int c = 0; c < 8; ++c) s[r][c] = 0.f;

    // ---- pass 1: scores (b128 reads, conflict-free pitch) ----
    #pragma unroll
    for (int c = 0; c < 8; ++c) {
        if (c <= cmax_blk) {
            __syncthreads();
            {
                const float* src = Kf + basek + (size_t)(c * 64 + jr) * ldk + d0;
                float4 a0 = ((const float4*)src)[0];
                float4 a1 = ((const float4*)src)[1];
                float4 a2 = ((const float4*)src)[2];
                float4 a3 = ((const float4*)src)[3];
                float4* dst = (float4*)(tile + jr * TP + d0);
                dst[0] = a0; dst[1] = a1; dst[2] = a2; dst[3] = a3;
            }
            __syncthreads();
            #pragma unroll
            for (int r = 0; r < RPW; ++r) {
                int kmaxr = row0 + r - mask0zp;
                if (c <= (kmaxr >> 6)) {
                    float acc = 0.f;
                    const float4* kt = (const float4*)(tile + lane * TP);
                    const float4* q4 = (const float4*)(qbuf[w][r]);
                    #pragma unroll
                    for (int dd = 0; dd < 16; ++dd) {
                        float4 kv = kt[dd];
                        float4 qv = q4[dd];
                        acc += qv.x * kv.x + qv.y * kv.y + qv.z * kv.z + qv.w * kv.w;
                    }
                    s[r][c] = acc;
                }
            }
        }
    }

    // ---- softmax1 -> decay -> softmax2 (registers) ----
    #pragma unroll
    for (int r = 0; r < RPW; ++r) {
        const int row = row0 + r;
        const int kmaxr = row - mask0zp;
        float sv[8], pc[8];
        float m = -1e30f;
        #pragma unroll
        for (int c = 0; c < 8; ++c) {
            int j = c * 64 + lane;
            sv[c] = (j <= kmaxr) ? s[r][c] * 0.125f : -1e30f;
            m = fmaxf(m, sv[c]);
        }
        m = wave_max(m);
        float sum = 0.f;
        #pragma unroll
        for (int c = 0; c < 8; ++c) {
            int j = c * 64 + lane;
            pc[c] = (j <= kmaxr) ? __expf(sv[c] - m) : 0.f;
            sum += pc[c];
        }
        sum = wave_sum(sum);
        float inv = 1.0f / sum;
        float run = 0.f;
        #pragma unroll
        for (int c = 0; c < 8; ++c) {
            float sc = pc[c] * inv;
            #pragma unroll
            for (int off = 1; off < 64; off <<= 1) {
                float tv = __shfl_up(sc, off, 64);
                if (lane >= off) sc += tv;
            }
            float distcum = run + sc;
            run += __shfl(sc, 63, 64);
            int j = c * 64 + lane;
            float rem = 1.0f - distcum;
            if (rem < 0.f) rem = 0.f;
            float prod = rem * (float)(row - j);
            if (prod < 0.f) prod = 0.f;
            float te = __expf(sqrtf(prod) * gamma);
            te = fminf(fmaxf(te, 1e-5f), 1e5f);
            sv[c] = (j <= kmaxr) ? sv[c] * te : -1e30f;
        }
        float m2 = -1e30f;
        #pragma unroll
        for (int c = 0; c < 8; ++c) m2 = fmaxf(m2, sv[c]);
        m2 = wave_max(m2);
        float sum2 = 0.f;
        #pragma unroll
        for (int c = 0; c < 8; ++c) {
            int j = c * 64 + lane;
            pc[c] = (j <= kmaxr) ? __expf(sv[c] - m2) : 0.f;
            sum2 += pc[c];
        }
        sum2 = wave_sum(sum2);
        float inv2 = 1.0f / sum2;
        #pragma unroll
        for (int c = 0; c < 8; ++c) s[r][c] = pc[c] * inv2;
    }

    // ---- pass 2: PV, lane = (key-group g, dim-quad l4), b128 V reads ----
    float4 o4[RPW];
    #pragma unroll
    for (int r = 0; r < RPW; ++r) o4[r] = make_float4(0.f, 0.f, 0.f, 0.f);
    #pragma unroll
    for (int c = 0; c < 8; ++c) {
        if (c <= cmax_blk) {
            __syncthreads();
            {
                const float* src = V + basev + (size_t)(c * 64 + jr) * ldv + d0;
                float4 a0 = ((const float4*)src)[0];
                float4 a1 = ((const float4*)src)[1];
                float4 a2 = ((const float4*)src)[2];
                float4 a3 = ((const float4*)src)[3];
                float4* dst = (float4*)(tile + jr * TP + d0);
                dst[0] = a0; dst[1] = a1; dst[2] = a2; dst[3] = a3;
            }
            __syncthreads();
            #pragma unroll
            for (int r = 0; r < RPW; ++r) {
                int kmaxr = row0 + r - mask0zp;
                if (c <= (kmaxr >> 6)) {
                    awbuf[w][lane] = s[r][c];
                    float4 acc = o4[r];
                    #pragma unroll
                    for (int j0 = 0; j0 < 16; ++j0) {
                        int j = g * 16 + j0;
                        float aj = awbuf[w][j];
                        float4 vv = *(const float4*)(tile + j * TP + l4 * 4);
                        acc.x += aj * vv.x; acc.y += aj * vv.y;
                        acc.z += aj * vv.z; acc.w += aj * vv.w;
                    }
                    o4[r] = acc;
                }
            }
        }
    }
    #pragma unroll
    for (int r = 0; r < RPW; ++r) {
        float4 v = o4[r];
        v.x += __shfl_xor(v.x, 16, 64); v.y += __shfl_xor(v.y, 16, 64);
        v.z += __shfl_xor(v.z, 16, 64); v.w += __shfl_xor(v.w, 16, 64);
        v.x += __shfl_xor(v.x, 32, 64); v.y += __shfl_xor(v.y, 32, 64);
        v.z += __shfl_xor(v.z, 32, 64); v.w += __shfl_xor(v.w, 32, 64);
        int row = row0 + r;
        if (lane < 16) {
            if (mask0zp && row == 0) v = make_float4(0.f, 0.f, 0.f, 0.f);
            *(float4*)(O + baseo + (size_t)row * DIM + lane * 4) = v;
        }
    }
}

static void run_wsplit(const float* W, u16* Bh, u16* Bl, int N, int K, int Npad,
                       hipStream_t stream) {
    wsplit<<<dim3(K / 64, Npad / 64), dim3(256), 0, stream>>>(W, Bh, Bl, N, K);
}
static void run_gemm(const float* A, const u16* Bth, const u16* Btl, int Krow, int koff,
                     const float* biasA, const float* biasB, int nsplit,
                     float* C, int N, int K, int mode, hipStream_t stream) {
    dim3 g((N + 63) / 64, TOK / 64);
    gemm_mf<<<g, dim3(256), 0, stream>>>(A, Bth, Btl, Krow, koff, biasA, biasB, nsplit, C, N, K, mode);
}

extern "C" void kernel_launch(void* const* d_in, const int* in_sizes, int n_in,
                              void* d_out, int out_size, void* d_ws, size_t ws_size,
                              hipStream_t stream) {
    (void)in_sizes; (void)n_in;
    const int* c_data    = (const int*)d_in[0];
    const int* ca_data   = (const int*)d_in[1];
    const float* c_emb   = (const float*)d_in[2];
    const float* ca_emb  = (const float*)d_in[3];
    const float* Wk  = (const float*)d_in[4];
    const float* bk  = (const float*)d_in[5];
    const float* Wv  = (const float*)d_in[6];
    const float* bv  = (const float*)d_in[7];
    const float* Wo  = (const float*)d_in[8];
    const float* bo  = (const float*)d_in[9];
    const float* gammas = (const float*)d_in[10];
    const float* ln1s = (const float*)d_in[11];
    const float* ln1b = (const float*)d_in[12];
    const float* W1  = (const float*)d_in[13];
    const float* b1  = (const float*)d_in[14];
    const float* W2  = (const float*)d_in[15];
    const float* b2  = (const float*)d_in[16];
    const float* ln2s = (const float*)d_in[17];
    const float* ln2b = (const float*)d_in[18];
    const float* oW0 = (const float*)d_in[19];
    const float* ob0 = (const float*)d_in[20];
    const float* oW1 = (const float*)d_in[21];
    const float* ob1 = (const float*)d_in[22];
    const float* oW2 = (const float*)d_in[23];
    const float* ob2 = (const float*)d_in[24];

    float* out = (float*)d_out;
    const size_t MB = 1024 * 1024;
    if (ws_size < 64 * MB) {
        VAKT_52226802319686_kernel<<<dim3((out_size + 255) / 256), dim3(256), 0, stream>>>(out, out_size);
        return;
    }
    char* wsp = (char*)d_ws;
    float* x0b = (float*)(wsp);             // 0-8
    float* yb  = (float*)(wsp + 8 * MB);    // 8-16
    float* xb  = (float*)(wsp + 16 * MB);   // 16-24
    float* qv  = (float*)(wsp + 24 * MB);   // 24-40: fused q|v (ld 1024) or q(24-32)+v(32-40)
    float* v2  = (float*)(wsp + 32 * MB);
    float* kb  = (float*)(wsp + 40 * MB);   // 40-48
    float* ao  = (float*)(wsp + 48 * MB);   // 48-56
    float* t1  = (float*)(wsp + 56 * MB);   // 56-64
    u16* btQ_h = (u16*)(wsp + 48 * MB);     // 1MB [1024][512] (dead before ao written)
    u16* btQ_l = (u16*)(wsp + 49 * MB);
    u16* btV_h = btQ_h + (size_t)512 * 512;
    u16* btV_l = btQ_l + (size_t)512 * 512;
    u16* btWo_h = (u16*)(wsp + 24 * MB);    // qv dead after attn
    u16* btWo_l = (u16*)(wsp + 25 * MB);
    u16* btW1_h = (u16*)(wsp + 24 * MB);
    u16* btW1_l = (u16*)(wsp + 26 * MB);
    u16* btW2_h = (u16*)(wsp + 28 * MB);
    u16* btW2_l = (u16*)(wsp + 30 * MB);
    float* ffc  = (float*)(wsp + 32 * MB);  // 32-48
    float* hcat = (float*)(wsp + 24 * MB);  // 24-40
    float* h1   = (float*)(wsp + 48 * MB);  // 48-56
    float* h2   = (float*)(wsp + 24 * MB);  // 24-40
    u16* btH_h  = (u16*)(wsp + 40 * MB);
    u16* btH_l  = (u16*)(wsp + 42 * MB);

    embed_r12<<<dim3(TOK), dim3(256), 0, stream>>>(c_data, ca_data, c_emb, ca_emb, x0b, yb);

    for (int li = 0; li < 6; ++li) {
        const float *in_q, *in_k, *in_v; float* outb; int m0; int pos;
        if (li == 0 || li == 1) { in_q = yb; in_k = x0b; in_v = yb; outb = yb; m0 = 0; pos = 1; }
        else if (li == 2) { in_q = x0b; in_k = x0b; in_v = x0b; outb = xb; m0 = 0; pos = 0; }
        else if (li == 3) { in_q = xb; in_k = xb; in_v = yb; outb = xb; m0 = 1; pos = 1; }
        else if (li == 4) { in_q = xb; in_k = xb; in_v = xb; outb = xb; m0 = 0; pos = 0; }
        else { in_q = xb; in_k = xb; in_v = yb; outb = xb; m0 = 1; pos = 1; }
        const float* query = in_q;  // for residual+LN

        run_wsplit(Wk + (size_t)li * DIM * DIM, btQ_h, btQ_l, DIM, DIM, DIM, stream);
        run_wsplit(Wv + (size_t)li * DIM * DIM, btV_h, btV_l, DIM, DIM, DIM, stream);

        const float *qp, *kp, *vp; int ldq, ldk, ldv;
        if (in_v == in_q) {
            // fused q|v projection, N=1024
            run_gemm(in_q, btQ_h, btQ_l, DIM, 0, bk + li * DIM, bv + li * DIM, DIM,
                     qv, 1024, DIM, 0, stream);
            qp = qv; ldq = 1024; vp = qv + 512; ldv = 1024;
            if (in_k == in_q) { kp = qv; ldk = 1024; }
            else {
                run_gemm(in_k, btQ_h, btQ_l, DIM, 0, bk + li * DIM, bk + li * DIM, DIM,
                         kb, DIM, DIM, 0, stream);
                kp = kb; ldk = DIM;
            }
        } else {
            // L3/5: q=k from in_q; v from in_v
            run_gemm(in_q, btQ_h, btQ_l, DIM, 0, bk + li * DIM, bk + li * DIM, DIM,
                     qv, DIM, DIM, 0, stream);
            run_gemm(in_v, btV_h, btV_l, DIM, 0, bv + li * DIM, bv + li * DIM, DIM,
                     v2, DIM, DIM, 0, stream);
            qp = qv; ldq = DIM; kp = qv; ldk = DIM; vp = v2; ldv = DIM;
        }
        attn_r12<<<dim3(SEQ / RPB, NHEAD, BATCH), dim3(256), 0, stream>>>(
            qp, ldq, kp, ldk, vp, ldv, gammas + li * NHEAD, ao, m0);
        run_wsplit(Wo + (size_t)li * DIM * DIM, btWo_h, btWo_l, DIM, DIM, DIM, stream);
        run_gemm(ao, btWo_h, btWo_l, DIM, 0, bo + li * DIM, bo + li * DIM, DIM,
                 t1, DIM, DIM, 0, stream);
        add_ln_r12<<<dim3(TOK / 4), dim3(256), 0, stream>>>(query, t1, ln1s + li * DIM, ln1b + li * DIM, outb);
        if (pos) {
            run_wsplit(W1 + (size_t)li * DIM * FFD, btW1_h, btW1_l, FFD, DIM, FFD, stream);
            run_wsplit(W2 + (size_t)li * FFD * DIM, btW2_h, btW2_l, DIM, FFD, DIM, stream);
            for (int c = 0; c < 2; ++c) {
                run_gemm(outb, btW1_h + (size_t)c * 1024 * DIM, btW1_l + (size_t)c * 1024 * DIM,
                         DIM, 0, b1 + li * FFD + c * 1024, b1 + li * FFD + c * 1024, 2048,
                         ffc, 1024, DIM, 1, stream);
                run_gemm(ffc, btW2_h, btW2_l, FFD, c * 1024, b2 + li * DIM, b2 + li * DIM, 2048,
                         t1, DIM, 1024, (c == 0) ? 0 : 2, stream);
            }
            add_ln_r12<<<dim3(TOK / 4), dim3(256), 0, stream>>>(outb, t1, ln2s + li * DIM, ln2b + li * DIM, outb);
        }
    }

    concat_r12<<<dim3(TOK), dim3(256), 0, stream>>>(xb, x0b, hcat);
    run_wsplit(oW0, btH_h, btH_l, 512, 1024, 512, stream);
    run_gemm(hcat, btH_h, btH_l, 1024, 0, ob0, ob0, 2048, h1, 512, 1024, 1, stream);
    run_wsplit(oW1, btH_h, btH_l, 1024, 512, 1024, stream);
    run_gemm(h1, btH_h, btH_l, 512, 0, ob1, ob1, 2048, h2, 1024, 512, 1, stream);
    run_wsplit(oW2, btH_h, btH_l, 1000, 1024, 1024, stream);
    run_gemm(h2, btH_h, btH_l, 1024, 0, ob2, ob2, 2048, out, 1000, 1024, 0, stream);
}